// Round 3
// baseline (156.532 us; speedup 1.0000x reference)
//
#include <hip/hip_runtime.h>

#define M_DIM 64
#define K_DIM 8192
#define N_DIM 10240
#define KSPLIT 4
#define KW (K_DIM / KSPLIT / 4)   // 512 k-elems per wave
#define NITER (KW / 32)           // 16 iterations

typedef __attribute__((ext_vector_type(8))) short short8;
typedef __attribute__((ext_vector_type(4))) float f32x4;
typedef __attribute__((ext_vector_type(4))) int i32x4;

// exact for integer-valued floats |v| <= 127 (<= 7 significant bits)
static __device__ __forceinline__ ushort f2bf_trunc(float f) {
    return (ushort)(__float_as_uint(f) >> 16);
}

// ---------------- Kernel 1: per-token dynamic int8 quantization ----------------
__global__ __launch_bounds__(256) void quant_kernel(
    const float* __restrict__ x,
    ushort* __restrict__ xq,
    float* __restrict__ xscale) {
    const int m = blockIdx.x;
    const int tid = threadIdx.x;
    const float4* xrow = (const float4*)(x + m * K_DIM);  // 2048 x float4
    float4 c[8];
    float mx = 0.f;
#pragma unroll
    for (int i = 0; i < 8; ++i) {
        c[i] = xrow[i * 256 + tid];
        mx = fmaxf(mx, fmaxf(fmaxf(fabsf(c[i].x), fabsf(c[i].y)),
                             fmaxf(fabsf(c[i].z), fabsf(c[i].w))));
    }
#pragma unroll
    for (int off = 32; off; off >>= 1) mx = fmaxf(mx, __shfl_xor(mx, off));
    __shared__ float wmax[4];
    if ((tid & 63) == 0) wmax[tid >> 6] = mx;
    __syncthreads();
    mx = fmaxf(fmaxf(wmax[0], wmax[1]), fmaxf(wmax[2], wmax[3]));
    const float s = mx / 127.0f;  // matches reference x_scale exactly
    if (tid == 0) xscale[m] = s;

    ushort4* qrow = (ushort4*)(xq + m * K_DIM);
#pragma unroll
    for (int i = 0; i < 8; ++i) {
        float q0 = fminf(fmaxf(rintf(c[i].x / s), -127.f), 127.f);
        float q1 = fminf(fmaxf(rintf(c[i].y / s), -127.f), 127.f);
        float q2 = fminf(fmaxf(rintf(c[i].z / s), -127.f), 127.f);
        float q3 = fminf(fmaxf(rintf(c[i].w / s), -127.f), 127.f);
        ushort4 o;
        o.x = f2bf_trunc(q0);
        o.y = f2bf_trunc(q1);
        o.z = f2bf_trunc(q2);
        o.w = f2bf_trunc(q3);
        qrow[i * 256 + tid] = o;
    }
}

// ---------------- Kernel 2: int8-as-bf16 MFMA GEMM, split-K partials -----------
// grid = (N/16, KSPLIT); 4 waves/block sub-split the block's K-range.
// Weights streamed with non-temporal loads (no L2 pollution of xq).
__global__ __launch_bounds__(256, 4) void gemm_kernel(
    const ushort* __restrict__ xq,      // bf16 bits [64, 8192]
    const int* __restrict__ W,          // int32 [10240, 8192], values in [-127,127]
    float* __restrict__ partials) {     // f32 [KSPLIT][64][10240] raw sums
    const int tid = threadIdx.x;
    const int wave = tid >> 6;
    const int lane = tid & 63;
    const int r16 = lane & 15;
    const int kgrp = lane >> 4;
    const int n0 = blockIdx.x << 4;
    const int kb = blockIdx.y;

    f32x4 acc[4];
#pragma unroll
    for (int i = 0; i < 4; ++i) acc[i] = (f32x4){0.f, 0.f, 0.f, 0.f};

    const int kbeg = kb * (K_DIM / KSPLIT) + wave * KW + kgrp * 8;
    const int* wp = W + (size_t)(n0 + r16) * K_DIM + kbeg;
    const ushort* ap = xq + r16 * K_DIM + kbeg;

    i32x4 b0 = __builtin_nontemporal_load((const i32x4*)wp);
    i32x4 b1 = __builtin_nontemporal_load((const i32x4*)wp + 1);

#pragma unroll 3
    for (int it = 0; it < NITER - 1; ++it) {
        i32x4 nb0 = __builtin_nontemporal_load((const i32x4*)(wp + 32));
        i32x4 nb1 = __builtin_nontemporal_load((const i32x4*)(wp + 32) + 1);
        short8 a0 = *(const short8*)(ap);
        short8 a1 = *(const short8*)(ap + 16 * K_DIM);
        short8 a2 = *(const short8*)(ap + 32 * K_DIM);
        short8 a3 = *(const short8*)(ap + 48 * K_DIM);
        short8 bf;
#pragma unroll
        for (int i = 0; i < 4; ++i)
            bf[i] = (short)(__float_as_uint((float)b0[i]) >> 16);  // exact, |v|<=127
#pragma unroll
        for (int i = 0; i < 4; ++i)
            bf[4 + i] = (short)(__float_as_uint((float)b1[i]) >> 16);
        acc[0] = __builtin_amdgcn_mfma_f32_16x16x32_bf16(a0, bf, acc[0], 0, 0, 0);
        acc[1] = __builtin_amdgcn_mfma_f32_16x16x32_bf16(a1, bf, acc[1], 0, 0, 0);
        acc[2] = __builtin_amdgcn_mfma_f32_16x16x32_bf16(a2, bf, acc[2], 0, 0, 0);
        acc[3] = __builtin_amdgcn_mfma_f32_16x16x32_bf16(a3, bf, acc[3], 0, 0, 0);
        wp += 32;
        ap += 32;
        b0 = nb0;
        b1 = nb1;
    }
    {   // final iteration (no prefetch)
        short8 a0 = *(const short8*)(ap);
        short8 a1 = *(const short8*)(ap + 16 * K_DIM);
        short8 a2 = *(const short8*)(ap + 32 * K_DIM);
        short8 a3 = *(const short8*)(ap + 48 * K_DIM);
        short8 bf;
#pragma unroll
        for (int i = 0; i < 4; ++i)
            bf[i] = (short)(__float_as_uint((float)b0[i]) >> 16);
#pragma unroll
        for (int i = 0; i < 4; ++i)
            bf[4 + i] = (short)(__float_as_uint((float)b1[i]) >> 16);
        acc[0] = __builtin_amdgcn_mfma_f32_16x16x32_bf16(a0, bf, acc[0], 0, 0, 0);
        acc[1] = __builtin_amdgcn_mfma_f32_16x16x32_bf16(a1, bf, acc[1], 0, 0, 0);
        acc[2] = __builtin_amdgcn_mfma_f32_16x16x32_bf16(a2, bf, acc[2], 0, 0, 0);
        acc[3] = __builtin_amdgcn_mfma_f32_16x16x32_bf16(a3, bf, acc[3], 0, 0, 0);
    }

    // cross-wave (sub-K) reduce in LDS; +1-pad inner dim to kill 4-way conflicts
    __shared__ float red[4][64][17];
#pragma unroll
    for (int mt = 0; mt < 4; ++mt)
#pragma unroll
        for (int j = 0; j < 4; ++j)
            red[wave][mt * 16 + kgrp * 4 + j][r16] = acc[mt][j];
    __syncthreads();

#pragma unroll
    for (int i = 0; i < 4; ++i) {
        int flat = tid + 256 * i;  // 0..1023 -> (m, nl)
        int m = flat >> 4;
        int nl = flat & 15;
        float sum = red[0][m][nl] + red[1][m][nl] + red[2][m][nl] + red[3][m][nl];
        partials[((size_t)kb * M_DIM + m) * N_DIM + n0 + nl] = sum;
    }
}

// ---------------- Kernel 3: split-K reduce + dequant + bias --------------------
__global__ __launch_bounds__(256) void reduce_kernel(
    const float* __restrict__ partials,
    const float* __restrict__ xscale,
    const float* __restrict__ wscale,
    const float* __restrict__ bias,
    float* __restrict__ out) {
    const int idx = blockIdx.x * 256 + threadIdx.x;  // 0 .. 64*2560-1
    const int m = idx / (N_DIM / 4);
    const int c = idx - m * (N_DIM / 4);
    const f32x4* P = (const f32x4*)partials;
    f32x4 s = P[(size_t)(0 * M_DIM + m) * (N_DIM / 4) + c];
    s += P[(size_t)(1 * M_DIM + m) * (N_DIM / 4) + c];
    s += P[(size_t)(2 * M_DIM + m) * (N_DIM / 4) + c];
    s += P[(size_t)(3 * M_DIM + m) * (N_DIM / 4) + c];
    f32x4 ws = ((const f32x4*)wscale)[c];
    f32x4 bs = ((const f32x4*)bias)[c];
    const float xs = xscale[m];
    f32x4 o = s * xs * ws + bs;
    ((f32x4*)out)[idx] = o;
}

extern "C" void kernel_launch(void* const* d_in, const int* in_sizes, int n_in,
                              void* d_out, int out_size, void* d_ws, size_t ws_size,
                              hipStream_t stream) {
    const float* x = (const float*)d_in[0];
    const int* W = (const int*)d_in[1];
    const float* wscale = (const float*)d_in[2];
    const float* bias = (const float*)d_in[3];
    float* out = (float*)d_out;

    float* xscale = (float*)d_ws;                                  // 256 B
    ushort* xq = (ushort*)((char*)d_ws + 4096);                    // 1 MB
    float* partials = (float*)((char*)d_ws + 2097152);             // 10.5 MB

    quant_kernel<<<M_DIM, 256, 0, stream>>>(x, xq, xscale);
    gemm_kernel<<<dim3(N_DIM / 16, KSPLIT), 256, 0, stream>>>(xq, W, partials);
    reduce_kernel<<<(M_DIM * N_DIM / 4) / 256, 256, 0, stream>>>(
        partials, xscale, wscale, bias, out);
}

// Round 4
// 111.972 us; speedup vs baseline: 1.3980x; 1.3980x over previous
//
#include <hip/hip_runtime.h>

#define M_DIM 64
#define K_DIM 8192
#define N_DIM 10240
#define KSPLIT 16
#define KBLK (K_DIM / KSPLIT)   // 512 k per block
#define NTILE 64                 // n columns per block (4 waves x 16)

typedef __attribute__((ext_vector_type(8))) short short8;
typedef __attribute__((ext_vector_type(4))) float f32x4;
typedef __attribute__((ext_vector_type(4))) int i32x4;

// exact for integer-valued floats |v| <= 127
static __device__ __forceinline__ ushort f2bf_trunc(float f) {
    return (ushort)(__float_as_uint(f) >> 16);
}

// ---------------- Kernel 1: per-token dynamic int8 quantization ----------------
__global__ __launch_bounds__(256) void quant_kernel(
    const float* __restrict__ x,
    ushort* __restrict__ xq,
    float* __restrict__ xscale) {
    const int m = blockIdx.x;
    const int tid = threadIdx.x;
    const float4* xrow = (const float4*)(x + m * K_DIM);  // 2048 x float4
    float4 c[8];
    float mx = 0.f;
#pragma unroll
    for (int i = 0; i < 8; ++i) {
        c[i] = xrow[i * 256 + tid];
        mx = fmaxf(mx, fmaxf(fmaxf(fabsf(c[i].x), fabsf(c[i].y)),
                             fmaxf(fabsf(c[i].z), fabsf(c[i].w))));
    }
#pragma unroll
    for (int off = 32; off; off >>= 1) mx = fmaxf(mx, __shfl_xor(mx, off));
    __shared__ float wmax[4];
    if ((tid & 63) == 0) wmax[tid >> 6] = mx;
    __syncthreads();
    mx = fmaxf(fmaxf(wmax[0], wmax[1]), fmaxf(wmax[2], wmax[3]));
    const float s = mx / 127.0f;  // matches reference x_scale exactly
    if (tid == 0) xscale[m] = s;

    ushort4* qrow = (ushort4*)(xq + m * K_DIM);
#pragma unroll
    for (int i = 0; i < 8; ++i) {
        float q0 = fminf(fmaxf(rintf(c[i].x / s), -127.f), 127.f);
        float q1 = fminf(fmaxf(rintf(c[i].y / s), -127.f), 127.f);
        float q2 = fminf(fmaxf(rintf(c[i].z / s), -127.f), 127.f);
        float q3 = fminf(fmaxf(rintf(c[i].w / s), -127.f), 127.f);
        ushort4 o;
        o.x = f2bf_trunc(q0);
        o.y = f2bf_trunc(q1);
        o.z = f2bf_trunc(q2);
        o.w = f2bf_trunc(q3);
        qrow[i * 256 + tid] = o;
    }
}

// ---------------- Kernel 2: LDS-staged A, burst-W MFMA GEMM --------------------
// grid = (N/64, KSPLIT). Block: 4 waves; wave w owns n-cols [n0+16w, n0+16w+16).
// A-tile xq[0:64, k0:k0+512] staged once in LDS (XOR-swizzled). W streamed in
// one 2KB-per-row register burst per wave (DRAM page locality).
__global__ __launch_bounds__(256, 2) void gemm_kernel(
    const ushort* __restrict__ xq,      // bf16 bits [64, 8192]
    const int* __restrict__ W,          // int32 [10240, 8192], |v| <= 127
    float* __restrict__ partials) {     // f32 [KSPLIT][64][10240] raw int sums
    const int tid = threadIdx.x;
    const int w = tid >> 6;
    const int lane = tid & 63;
    const int r16 = lane & 15;
    const int kgrp = lane >> 4;
    const int n0 = blockIdx.x * NTILE;
    const int kb = blockIdx.y;
    const int k0 = kb * KBLK;

    __shared__ __align__(16) ushort Alds[M_DIM * KBLK];  // 64 KB

    // ---- stage A: each wave stages 16 rows, 1 KB (one row) per instruction,
    // global side perfectly coalesced; LDS side XOR-swizzled (chunk ^= row&7).
#pragma unroll
    for (int j = 0; j < 16; ++j) {
        const int row = w * 16 + j;
        short8 v = *(const short8*)(xq + row * K_DIM + k0 + lane * 8);
        const int sw = lane ^ (row & 7);
        *(short8*)(&Alds[row * KBLK + sw * 8]) = v;
    }
    __syncthreads();

    f32x4 acc[4];
#pragma unroll
    for (int i = 0; i < 4; ++i) acc[i] = (f32x4){0.f, 0.f, 0.f, 0.f};

    // ---- burst-load the wave's full W slice: 16 rows x 2 KB contiguous each
    const int* wp = W + (size_t)(n0 + w * 16 + r16) * K_DIM + k0 + kgrp * 8;
    i32x4 wb[16][2];
#pragma unroll
    for (int s = 0; s < 16; ++s) {
        wb[s][0] = *(const i32x4*)(wp + s * 32);
        wb[s][1] = *(const i32x4*)(wp + s * 32 + 4);
    }

    // ---- 16 k-steps of 32: cvt W frag, ds_read 4 A frags, 4 MFMA
#pragma unroll
    for (int s = 0; s < 16; ++s) {
        short8 bf;
#pragma unroll
        for (int i = 0; i < 4; ++i) {
            bf[i] = (short)(__float_as_uint((float)wb[s][0][i]) >> 16);
            bf[4 + i] = (short)(__float_as_uint((float)wb[s][1][i]) >> 16);
        }
#pragma unroll
        for (int mt = 0; mt < 4; ++mt) {
            const int row = mt * 16 + r16;
            const int chunk = s * 4 + kgrp;
            short8 a = *(const short8*)(
                &Alds[row * KBLK + (chunk ^ (row & 7)) * 8]);
            acc[mt] = __builtin_amdgcn_mfma_f32_16x16x32_bf16(a, bf, acc[mt], 0, 0, 0);
        }
    }

    // ---- epilogue: stage C in LDS (reuse A buffer) for coalesced stores
    __syncthreads();  // all waves done reading Alds
    float* Clds = (float*)Alds;  // [64 m][64 n] f32 = 16 KB
#pragma unroll
    for (int mt = 0; mt < 4; ++mt)
#pragma unroll
        for (int j = 0; j < 4; ++j) {
            const int m = mt * 16 + kgrp * 4 + j;
            Clds[m * 64 + w * 16 + r16] = acc[mt][j];
        }
    __syncthreads();
    float* pbase = partials + (size_t)kb * (M_DIM * N_DIM);
#pragma unroll
    for (int i = 0; i < 4; ++i) {
        const int idx = tid + 256 * i;  // 0..1023 -> (m, 16B-chunk)
        const int m = idx >> 4;
        const int ch = idx & 15;
        f32x4 v = ((const f32x4*)Clds)[idx];
        *(f32x4*)(pbase + m * N_DIM + n0 + ch * 4) = v;
    }
}

// ---------------- Kernel 3: split-K reduce + dequant + bias --------------------
__global__ __launch_bounds__(256) void reduce_kernel(
    const float* __restrict__ partials,
    const float* __restrict__ xscale,
    const float* __restrict__ wscale,
    const float* __restrict__ bias,
    float* __restrict__ out) {
    const int idx = blockIdx.x * 256 + threadIdx.x;  // 0 .. 64*2560-1
    const int m = idx / (N_DIM / 4);
    const int c = idx - m * (N_DIM / 4);
    const f32x4* P = (const f32x4*)partials;
    f32x4 s = (f32x4){0.f, 0.f, 0.f, 0.f};
#pragma unroll
    for (int p = 0; p < KSPLIT; ++p)
        s += P[((size_t)p * M_DIM + m) * (N_DIM / 4) + c];
    f32x4 ws = ((const f32x4*)wscale)[c];
    f32x4 bs = ((const f32x4*)bias)[c];
    const float xs = xscale[m];
    f32x4 o = s * xs * ws + bs;
    ((f32x4*)out)[idx] = o;
}

extern "C" void kernel_launch(void* const* d_in, const int* in_sizes, int n_in,
                              void* d_out, int out_size, void* d_ws, size_t ws_size,
                              hipStream_t stream) {
    const float* x = (const float*)d_in[0];
    const int* W = (const int*)d_in[1];
    const float* wscale = (const float*)d_in[2];
    const float* bias = (const float*)d_in[3];
    float* out = (float*)d_out;

    float* xscale = (float*)d_ws;                       // 256 B
    ushort* xq = (ushort*)((char*)d_ws + 4096);         // 1 MB
    float* partials = (float*)((char*)d_ws + 2097152);  // 42 MB

    quant_kernel<<<M_DIM, 256, 0, stream>>>(x, xq, xscale);
    gemm_kernel<<<dim3(N_DIM / NTILE, KSPLIT), 256, 0, stream>>>(xq, W, partials);
    reduce_kernel<<<(M_DIM * N_DIM / 4) / 256, 256, 0, stream>>>(
        partials, xscale, wscale, bias, out);
}

// Round 5
// 92.286 us; speedup vs baseline: 1.6962x; 1.2133x over previous
//
#include <hip/hip_runtime.h>

#define M_DIM 64
#define K_DIM 8192
#define N_DIM 10240
#define KSPLIT 8
#define KBLK (K_DIM / KSPLIT)    // 1024 k per block
#define KSTEP 256                 // k per chunk (ints)
#define NCHUNK (KBLK / KSTEP)     // 4
#define NTILE 64                  // n rows per block

typedef __attribute__((ext_vector_type(8))) short short8;
typedef __attribute__((ext_vector_type(4))) float f32x4;
typedef __attribute__((ext_vector_type(4))) int i32x4;

// exact for integer-valued floats |v| <= 127
static __device__ __forceinline__ ushort f2bf_trunc(float f) {
    return (ushort)(__float_as_uint(f) >> 16);
}

// ---------------- Kernel 1: per-token dynamic int8 quantization ----------------
__global__ __launch_bounds__(256) void quant_kernel(
    const float* __restrict__ x,
    ushort* __restrict__ xq,
    float* __restrict__ xscale) {
    const int m = blockIdx.x;
    const int tid = threadIdx.x;
    const float4* xrow = (const float4*)(x + m * K_DIM);
    float4 c[8];
    float mx = 0.f;
#pragma unroll
    for (int i = 0; i < 8; ++i) {
        c[i] = xrow[i * 256 + tid];
        mx = fmaxf(mx, fmaxf(fmaxf(fabsf(c[i].x), fabsf(c[i].y)),
                             fmaxf(fabsf(c[i].z), fabsf(c[i].w))));
    }
#pragma unroll
    for (int off = 32; off; off >>= 1) mx = fmaxf(mx, __shfl_xor(mx, off));
    __shared__ float wmax[4];
    if ((tid & 63) == 0) wmax[tid >> 6] = mx;
    __syncthreads();
    mx = fmaxf(fmaxf(wmax[0], wmax[1]), fmaxf(wmax[2], wmax[3]));
    const float s = mx / 127.0f;
    if (tid == 0) xscale[m] = s;

    ushort4* qrow = (ushort4*)(xq + m * K_DIM);
#pragma unroll
    for (int i = 0; i < 8; ++i) {
        float q0 = fminf(fmaxf(rintf(c[i].x / s), -127.f), 127.f);
        float q1 = fminf(fmaxf(rintf(c[i].y / s), -127.f), 127.f);
        float q2 = fminf(fmaxf(rintf(c[i].z / s), -127.f), 127.f);
        float q3 = fminf(fmaxf(rintf(c[i].w / s), -127.f), 127.f);
        ushort4 o;
        o.x = f2bf_trunc(q0);
        o.y = f2bf_trunc(q1);
        o.z = f2bf_trunc(q2);
        o.w = f2bf_trunc(q3);
        qrow[i * 256 + tid] = o;
    }
}

// ---------------- Kernel 2: stream-linear W, LDS-tiled MFMA GEMM ---------------
// grid (N/64, KSPLIT), 4 waves. Chunked k (KSTEP=256): W read 1KB-contiguous
// per instruction (copy-bench pattern); reg-staged cvt int32->bf16 -> swizzled
// LDS; double-buffered A/B chunk tiles; wave w owns n-cols [n0+16w, +16).
__global__ __launch_bounds__(256, 1) void gemm_kernel(
    const ushort* __restrict__ xq,   // bf16 bits [64, 8192]
    const int* __restrict__ W,       // int32 [10240, 8192], |v| <= 127
    float* __restrict__ partials) {  // f32 [KSPLIT][64][10240]
    const int tid = threadIdx.x;
    const int w = tid >> 6;
    const int lane = tid & 63;
    const int r16 = lane & 15;
    const int kgrp = lane >> 4;
    const int n0 = blockIdx.x * NTILE;
    const int kb = blockIdx.y;
    const int k0 = kb * KBLK;

    __shared__ __align__(16) ushort Abuf[2][NTILE * KSTEP];  // 2 x 32 KB
    __shared__ __align__(16) ushort Bbuf[2][NTILE * KSTEP];  // 2 x 32 KB

    short8 aA[8];   // A chunk staging: 8 x 16B/lane
    i32x4 aB[16];   // W chunk staging: 16 x 16B/lane (1KB/instr contiguous)

#define ISSUE_B(c)                                                            \
    {                                                                         \
        const int* base = W + k0 + (c) * KSTEP;                               \
        _Pragma("unroll") for (int i = 0; i < 16; ++i) {                      \
            const int row = n0 + w * 16 + i;                                  \
            aB[i] = *(const i32x4*)(base + (size_t)row * K_DIM + lane * 4);   \
        }                                                                     \
    }
#define ISSUE_A(c)                                                            \
    {                                                                         \
        const ushort* base = xq + k0 + (c) * KSTEP;                           \
        _Pragma("unroll") for (int i = 0; i < 8; ++i) {                       \
            const int row = w * 16 + i * 2 + (lane >> 5);                     \
            aA[i] = *(const short8*)(base + row * K_DIM + (lane & 31) * 8);   \
        }                                                                     \
    }
#define WRITE_A(buf)                                                          \
    {                                                                         \
        _Pragma("unroll") for (int i = 0; i < 8; ++i) {                       \
            const int row = w * 16 + i * 2 + (lane >> 5);                     \
            const int off = ((lane & 31) * 16) ^ ((row & 7) << 4);            \
            *(short8*)((char*)&Abuf[buf][row * KSTEP] + off) = aA[i];         \
        }                                                                     \
    }
#define WRITE_B(buf)                                                          \
    {                                                                         \
        _Pragma("unroll") for (int i = 0; i < 16; ++i) {                      \
            const int row = w * 16 + i;                                       \
            ushort4 h;                                                        \
            h.x = f2bf_trunc((float)aB[i][0]);                                \
            h.y = f2bf_trunc((float)aB[i][1]);                                \
            h.z = f2bf_trunc((float)aB[i][2]);                                \
            h.w = f2bf_trunc((float)aB[i][3]);                                \
            const int off = (lane * 8) ^ ((row & 7) << 4);                    \
            *(ushort4*)((char*)&Bbuf[buf][row * KSTEP] + off) = h;            \
        }                                                                     \
    }

    f32x4 acc[4];
#pragma unroll
    for (int i = 0; i < 4; ++i) acc[i] = (f32x4){0.f, 0.f, 0.f, 0.f};

    // prologue: chunk 0 staged, chunk 1 in flight
    ISSUE_B(0)
    ISSUE_A(0)
    WRITE_A(0)
    WRITE_B(0)
    __syncthreads();
    ISSUE_B(1)
    ISSUE_A(1)
    asm volatile("" ::: "memory");  // keep prefetch issue ahead of compute

#pragma unroll
    for (int c = 0; c < NCHUNK; ++c) {
        const int buf = c & 1;
        // compute chunk c: 8 k-steps x (1 B-frag + 4 A-frags + 4 MFMA)
#pragma unroll
        for (int ks = 0; ks < 8; ++ks) {
            const int koff = ks * 64;
            const int swz = (koff + kgrp * 16) ^ ((r16 & 7) << 4);
            short8 bfrag = *(const short8*)(
                (char*)&Bbuf[buf][(w * 16 + r16) * KSTEP] + swz);
#pragma unroll
            for (int mt = 0; mt < 4; ++mt) {
                short8 afrag = *(const short8*)(
                    (char*)&Abuf[buf][(mt * 16 + r16) * KSTEP] + swz);
                acc[mt] = __builtin_amdgcn_mfma_f32_16x16x32_bf16(
                    afrag, bfrag, acc[mt], 0, 0, 0);
            }
        }
        if (c < NCHUNK - 1) {
            __syncthreads();  // all waves done reading buf (c+1)&1's old data
            WRITE_A((c + 1) & 1)
            WRITE_B((c + 1) & 1)
            if (c + 2 < NCHUNK) {
                ISSUE_B(c + 2)
                ISSUE_A(c + 2)
                asm volatile("" ::: "memory");
            }
            __syncthreads();  // new chunk visible
        }
    }

    // epilogue: C via LDS for coalesced partials write
    __syncthreads();
    float* Cl = (float*)&Abuf[0][0];  // [64 m][64 n] f32 = 16 KB
#pragma unroll
    for (int mt = 0; mt < 4; ++mt)
#pragma unroll
        for (int j = 0; j < 4; ++j)
            Cl[(mt * 16 + kgrp * 4 + j) * 64 + w * 16 + r16] = acc[mt][j];
    __syncthreads();
    float* pb = partials + (size_t)kb * (M_DIM * N_DIM);
#pragma unroll
    for (int i = 0; i < 4; ++i) {
        const int idx = tid + 256 * i;
        const int m = idx >> 4;
        const int ch = idx & 15;
        *(f32x4*)(pb + m * N_DIM + n0 + ch * 4) = ((const f32x4*)Cl)[idx];
    }
#undef ISSUE_B
#undef ISSUE_A
#undef WRITE_A
#undef WRITE_B
}

// ---------------- Kernel 3: split-K reduce + dequant + bias --------------------
__global__ __launch_bounds__(256) void reduce_kernel(
    const float* __restrict__ partials,
    const float* __restrict__ xscale,
    const float* __restrict__ wscale,
    const float* __restrict__ bias,
    float* __restrict__ out) {
    const int idx = blockIdx.x * 256 + threadIdx.x;  // 0 .. 64*2560-1
    const int m = idx / (N_DIM / 4);
    const int c = idx - m * (N_DIM / 4);
    const f32x4* P = (const f32x4*)partials;
    f32x4 s = (f32x4){0.f, 0.f, 0.f, 0.f};
#pragma unroll
    for (int p = 0; p < KSPLIT; ++p)
        s += P[((size_t)p * M_DIM + m) * (N_DIM / 4) + c];
    f32x4 ws = ((const f32x4*)wscale)[c];
    f32x4 bs = ((const f32x4*)bias)[c];
    const float xs = xscale[m];
    f32x4 o = s * xs * ws + bs;
    ((f32x4*)out)[idx] = o;
}

extern "C" void kernel_launch(void* const* d_in, const int* in_sizes, int n_in,
                              void* d_out, int out_size, void* d_ws, size_t ws_size,
                              hipStream_t stream) {
    const float* x = (const float*)d_in[0];
    const int* W = (const int*)d_in[1];
    const float* wscale = (const float*)d_in[2];
    const float* bias = (const float*)d_in[3];
    float* out = (float*)d_out;

    float* xscale = (float*)d_ws;                       // 256 B
    ushort* xq = (ushort*)((char*)d_ws + 4096);         // 1 MB
    float* partials = (float*)((char*)d_ws + 2097152);  // 21 MB

    quant_kernel<<<M_DIM, 256, 0, stream>>>(x, xq, xscale);
    gemm_kernel<<<dim3(N_DIM / NTILE, KSPLIT), 256, 0, stream>>>(xq, W, partials);
    reduce_kernel<<<(M_DIM * N_DIM / 4) / 256, 256, 0, stream>>>(
        partials, xscale, wscale, bias, out);
}